// Round 1
// baseline (338.209 us; speedup 1.0000x reference)
//
#include <hip/hip_runtime.h>
#include <hip/hip_bf16.h>

#define HID 1024
#define NH 16
#define DH 64
#define SEQ 2048
#define NB 4
#define MTOT (NB*SEQ)   // 8192

typedef __attribute__((ext_vector_type(4))) float f32x4;
typedef __attribute__((ext_vector_type(8))) __bf16 bf16x8;
typedef __attribute__((ext_vector_type(4))) __bf16 bf16x4;

__device__ __forceinline__ f32x4 mfma16(bf16x8 a, bf16x8 b, f32x4 c) {
    return __builtin_amdgcn_mfma_f32_16x16x32_bf16(a, b, c, 0, 0, 0);
}

__device__ __forceinline__ void gload16(const void* g, void* l) {
    __builtin_amdgcn_global_load_lds(
        (const __attribute__((address_space(1))) unsigned int*)g,
        (__attribute__((address_space(3))) unsigned int*)l, 16, 0, 0);
}

// ---------------- fp32 -> bf16 convert ----------------
__global__ __launch_bounds__(256)
void cvt(const float* __restrict__ in, __bf16* __restrict__ out, int n) {
    int i = (blockIdx.x * 256 + threadIdx.x) * 4;
    if (i >= n) return;
    float4 v = *(const float4*)(in + i);
    bf16x4 o = { (__bf16)v.x, (__bf16)v.y, (__bf16)v.z, (__bf16)v.w };
    *(bf16x4*)(out + i) = o;
}

// ---------------- GEMM: out[m,n] = sum_k A[m,k]*W[n,k] + bias[n] ----------------
// MODE 0: Q -> bf16 [B,H,S,D]   MODE 1: K -> bf16 [B,H,S,D]
// MODE 2: V -> bf16 [B,H,D,S] (transposed)   MODE 3: proj -> fp32 [M,HID]*hidden_z
template<int MODE>
__global__ __launch_bounds__(256)
void gemm_bt(const __bf16* __restrict__ A, const __bf16* __restrict__ W,
             const float* __restrict__ bias, const float* __restrict__ hz,
             void* __restrict__ outp)
{
    __shared__ __bf16 As[128 * 32];
    __shared__ __bf16 Bs[128 * 32];
    const int tid  = threadIdx.x;
    const int lane = tid & 63, wid = tid >> 6;
    const int m0 = blockIdx.x * 128;
    const int n0 = blockIdx.y * 128;
    const int wm = (wid >> 1) * 64, wn = (wid & 1) * 64;

    f32x4 acc[4][4];
    #pragma unroll
    for (int i = 0; i < 4; i++)
        #pragma unroll
        for (int j = 0; j < 4; j++) acc[i][j] = (f32x4){0.f, 0.f, 0.f, 0.f};

    for (int kt = 0; kt < HID; kt += 32) {
        // stage A,B tiles: 512 16B chunks each; LDS linear, source pre-swizzled
        #pragma unroll
        for (int i = 0; i < 2; i++) {
            int c = wid * 128 + i * 64 + lane;
            int row = c >> 2, slot = c & 3;
            int ss = slot ^ (row & 3);
            gload16(A + (size_t)(m0 + row) * HID + kt + ss * 8, (char*)As + c * 16);
            gload16(W + (size_t)(n0 + row) * HID + kt + ss * 8, (char*)Bs + c * 16);
        }
        __syncthreads();

        bf16x8 af[4], bfr[4];
        #pragma unroll
        for (int mi = 0; mi < 4; mi++) {
            int row = wm + mi * 16 + (lane & 15);
            int off = row * 64 + (((lane >> 4) * 16) ^ ((row & 3) << 4));
            af[mi] = *(const bf16x8*)((const char*)As + off);
        }
        #pragma unroll
        for (int ni = 0; ni < 4; ni++) {
            int row = wn + ni * 16 + (lane & 15);
            int off = row * 64 + (((lane >> 4) * 16) ^ ((row & 3) << 4));
            bfr[ni] = *(const bf16x8*)((const char*)Bs + off);
        }
        #pragma unroll
        for (int mi = 0; mi < 4; mi++)
            #pragma unroll
            for (int ni = 0; ni < 4; ni++)
                acc[mi][ni] = mfma16(af[mi], bfr[ni], acc[mi][ni]);
        __syncthreads();
    }

    #pragma unroll
    for (int mi = 0; mi < 4; mi++)
        #pragma unroll
        for (int ni = 0; ni < 4; ni++)
            #pragma unroll
            for (int r = 0; r < 4; r++) {
                int m = m0 + wm + mi * 16 + ((lane >> 4) * 4) + r;
                int n = n0 + wn + ni * 16 + (lane & 15);
                float v = acc[mi][ni][r] + bias[n];
                if (MODE == 3) {
                    ((float*)outp)[(size_t)m * HID + n] = v * hz[n];
                } else {
                    int b = m >> 11, s = m & (SEQ - 1);
                    int h = n >> 6,  d = n & 63;
                    size_t idx;
                    if (MODE == 2) idx = ((size_t)(b * NH + h) * DH + d) * SEQ + s;
                    else           idx = ((size_t)(b * NH + h) * SEQ + s) * DH + d;
                    ((__bf16*)outp)[idx] = (__bf16)v;
                }
            }
}

// ---------------- flash attention ----------------
// grid: (S/128, NH, NB); 256 threads = 4 waves; wave w owns q-rows [w*32, w*32+32)
__global__ __launch_bounds__(256)
void attn(const __bf16* __restrict__ Q, const __bf16* __restrict__ K,
          const __bf16* __restrict__ VT, const float* __restrict__ heads_z,
          __bf16* __restrict__ C)
{
    __shared__ __bf16 Ks[64 * 64];
    __shared__ __bf16 Vs[64 * 64];   // V^T tile: rows=d, cols=kv
    __shared__ __bf16 Ps[128 * 64];
    const int tid = threadIdx.x, lane = tid & 63, wid = tid >> 6;
    const int qb = blockIdx.x, h = blockIdx.y, b = blockIdx.z;
    const size_t bh = (size_t)(b * NH + h);
    const __bf16* Qg = Q + bh * SEQ * DH;
    const __bf16* Kg = K + bh * SEQ * DH;
    const __bf16* Vg = VT + bh * (size_t)DH * SEQ;
    const int q0 = qb * 128;

    // hoist Q fragments to registers
    bf16x8 qa[2][2];
    #pragma unroll
    for (int mi = 0; mi < 2; mi++)
        #pragma unroll
        for (int kf = 0; kf < 2; kf++) {
            int row = q0 + wid * 32 + mi * 16 + (lane & 15);
            qa[mi][kf] = *(const bf16x8*)(Qg + (size_t)row * DH + kf * 32 + (lane >> 4) * 8);
        }

    f32x4 ctx[2][4];
    float mrun[2][4], lrun[2][4];
    #pragma unroll
    for (int mi = 0; mi < 2; mi++) {
        #pragma unroll
        for (int ni = 0; ni < 4; ni++) ctx[mi][ni] = (f32x4){0.f, 0.f, 0.f, 0.f};
        #pragma unroll
        for (int r = 0; r < 4; r++) { mrun[mi][r] = -1e30f; lrun[mi][r] = 0.f; }
    }

    for (int kv0 = 0; kv0 < SEQ; kv0 += 64) {
        // stage K (contiguous 8KB) and V^T tiles, source pre-swizzled
        #pragma unroll
        for (int i = 0; i < 2; i++) {
            int c = wid * 128 + i * 64 + lane;
            int row = c >> 3, slot = c & 7;
            int ss = slot ^ (row & 7);
            gload16(Kg + (size_t)(kv0 + row) * DH + ss * 8, (char*)Ks + c * 16);
            gload16(Vg + (size_t)row * SEQ + kv0 + ss * 8, (char*)Vs + c * 16);
        }
        __syncthreads();

        // QK^T
        bf16x8 kb[4][2];
        #pragma unroll
        for (int ni = 0; ni < 4; ni++)
            #pragma unroll
            for (int kf = 0; kf < 2; kf++) {
                int row = ni * 16 + (lane & 15);
                int off = row * 128 + ((kf * 64 + (lane >> 4) * 16) ^ ((row & 7) << 4));
                kb[ni][kf] = *(const bf16x8*)((const char*)Ks + off);
            }
        f32x4 sf[2][4];
        #pragma unroll
        for (int mi = 0; mi < 2; mi++)
            #pragma unroll
            for (int ni = 0; ni < 4; ni++) {
                f32x4 t = (f32x4){0.f, 0.f, 0.f, 0.f};
                t = mfma16(qa[mi][0], kb[ni][0], t);
                t = mfma16(qa[mi][1], kb[ni][1], t);
                sf[mi][ni] = t * 0.125f;   // 1/sqrt(64)
            }

        // online softmax (rows spread over the 16-lane group: row=(l>>4)*4+r)
        #pragma unroll
        for (int mi = 0; mi < 2; mi++) {
            float nm[4], al[4], rs[4];
            #pragma unroll
            for (int r = 0; r < 4; r++) {
                float t = sf[mi][0][r];
                #pragma unroll
                for (int ni = 1; ni < 4; ni++) t = fmaxf(t, sf[mi][ni][r]);
                #pragma unroll
                for (int off = 1; off < 16; off <<= 1) t = fmaxf(t, __shfl_xor(t, off));
                nm[r] = fmaxf(mrun[mi][r], t);
                al[r] = __expf(mrun[mi][r] - nm[r]);
                mrun[mi][r] = nm[r];
                rs[r] = 0.f;
            }
            #pragma unroll
            for (int ni = 0; ni < 4; ni++)
                #pragma unroll
                for (int r = 0; r < 4; r++) {
                    float pv = __expf(sf[mi][ni][r] - nm[r]);
                    sf[mi][ni][r] = pv;
                    rs[r] += pv;
                }
            #pragma unroll
            for (int r = 0; r < 4; r++) {
                #pragma unroll
                for (int off = 1; off < 16; off <<= 1) rs[r] += __shfl_xor(rs[r], off);
                lrun[mi][r] = lrun[mi][r] * al[r] + rs[r];
            }
            #pragma unroll
            for (int ni = 0; ni < 4; ni++)
                #pragma unroll
                for (int r = 0; r < 4; r++) ctx[mi][ni][r] *= al[r];
            // write P (bf16) to swizzled LDS for PV re-layout
            #pragma unroll
            for (int ni = 0; ni < 4; ni++)
                #pragma unroll
                for (int r = 0; r < 4; r++) {
                    int row = wid * 32 + mi * 16 + (lane >> 4) * 4 + r;
                    int col = ni * 16 + (lane & 15);
                    int off = row * 128 + ((col * 2) ^ ((row & 7) << 4));
                    *(__bf16*)((char*)Ps + off) = (__bf16)sf[mi][ni][r];
                }
        }

        // PV: ctx[q][d] += sum_k P[q][k] * VT[d][k]
        bf16x8 pa[2][2], vb[4][2];
        #pragma unroll
        for (int mi = 0; mi < 2; mi++)
            #pragma unroll
            for (int kf = 0; kf < 2; kf++) {
                int row = wid * 32 + mi * 16 + (lane & 15);
                int off = row * 128 + ((kf * 64 + (lane >> 4) * 16) ^ ((row & 7) << 4));
                pa[mi][kf] = *(const bf16x8*)((const char*)Ps + off);
            }
        #pragma unroll
        for (int ni = 0; ni < 4; ni++)
            #pragma unroll
            for (int kf = 0; kf < 2; kf++) {
                int row = ni * 16 + (lane & 15);
                int off = row * 128 + ((kf * 64 + (lane >> 4) * 16) ^ ((row & 7) << 4));
                vb[ni][kf] = *(const bf16x8*)((const char*)Vs + off);
            }
        #pragma unroll
        for (int mi = 0; mi < 2; mi++)
            #pragma unroll
            for (int ni = 0; ni < 4; ni++) {
                ctx[mi][ni] = mfma16(pa[mi][0], vb[ni][0], ctx[mi][ni]);
                ctx[mi][ni] = mfma16(pa[mi][1], vb[ni][1], ctx[mi][ni]);
            }
        __syncthreads();
    }

    const float hzv = heads_z[h];
    #pragma unroll
    for (int mi = 0; mi < 2; mi++)
        #pragma unroll
        for (int ni = 0; ni < 4; ni++)
            #pragma unroll
            for (int r = 0; r < 4; r++) {
                int qrow = q0 + wid * 32 + mi * 16 + (lane >> 4) * 4 + r;
                int d = ni * 16 + (lane & 15);
                float v = ctx[mi][ni][r] / lrun[mi][r] * hzv;
                C[(size_t)(b * SEQ + qrow) * HID + h * DH + d] = (__bf16)v;
            }
}

extern "C" void kernel_launch(void* const* d_in, const int* in_sizes, int n_in,
                              void* d_out, int out_size, void* d_ws, size_t ws_size,
                              hipStream_t stream)
{
    const float* X    = (const float*)d_in[0];
    const float* Wq   = (const float*)d_in[1];
    const float* bq   = (const float*)d_in[2];
    const float* Wk   = (const float*)d_in[3];
    const float* bk   = (const float*)d_in[4];
    const float* Wv   = (const float*)d_in[5];
    const float* bv   = (const float*)d_in[6];
    const float* Wp   = (const float*)d_in[7];
    const float* bp   = (const float*)d_in[8];
    const float* hz   = (const float*)d_in[9];
    const float* hidz = (const float*)d_in[10];

    __bf16* ws  = (__bf16*)d_ws;
    __bf16* Xb  = ws;
    __bf16* Wqb = Xb  + (size_t)MTOT * HID;
    __bf16* Wkb = Wqb + (size_t)HID * HID;
    __bf16* Wvb = Wkb + (size_t)HID * HID;
    __bf16* Wpb = Wvb + (size_t)HID * HID;
    __bf16* Qb  = Wpb + (size_t)HID * HID;
    __bf16* Kb  = Qb  + (size_t)MTOT * HID;
    __bf16* VTb = Kb  + (size_t)MTOT * HID;
    __bf16* Cb  = VTb + (size_t)MTOT * HID;

    cvt<<<(MTOT * HID / 4 + 255) / 256, 256, 0, stream>>>(X,  Xb,  MTOT * HID);
    cvt<<<(HID * HID / 4 + 255) / 256, 256, 0, stream>>>(Wq, Wqb, HID * HID);
    cvt<<<(HID * HID / 4 + 255) / 256, 256, 0, stream>>>(Wk, Wkb, HID * HID);
    cvt<<<(HID * HID / 4 + 255) / 256, 256, 0, stream>>>(Wv, Wvb, HID * HID);
    cvt<<<(HID * HID / 4 + 255) / 256, 256, 0, stream>>>(Wp, Wpb, HID * HID);

    dim3 gg(MTOT / 128, HID / 128);
    gemm_bt<0><<<gg, 256, 0, stream>>>(Xb, Wqb, bq, nullptr, Qb);
    gemm_bt<1><<<gg, 256, 0, stream>>>(Xb, Wkb, bk, nullptr, Kb);
    gemm_bt<2><<<gg, 256, 0, stream>>>(Xb, Wvb, bv, nullptr, VTb);

    attn<<<dim3(SEQ / 128, NH, NB), 256, 0, stream>>>(Qb, Kb, VTb, hz, Cb);

    gemm_bt<3><<<gg, 256, 0, stream>>>(Cb, Wpb, bp, hidz, d_out);
}

// Round 2
// 220.903 us; speedup vs baseline: 1.5310x; 1.5310x over previous
//
#include <hip/hip_runtime.h>
#include <hip/hip_bf16.h>

#define HID 1024
#define NH 16
#define DH 64
#define SEQ 2048
#define NB 4
#define MTOT (NB*SEQ)   // 8192

typedef __attribute__((ext_vector_type(4))) float f32x4;
typedef __attribute__((ext_vector_type(8))) __bf16 bf16x8;
typedef __attribute__((ext_vector_type(4))) __bf16 bf16x4;

__device__ __forceinline__ f32x4 mfma16(bf16x8 a, bf16x8 b, f32x4 c) {
    return __builtin_amdgcn_mfma_f32_16x16x32_bf16(a, b, c, 0, 0, 0);
}

__device__ __forceinline__ void gload16(const void* g, void* l) {
    __builtin_amdgcn_global_load_lds(
        (const __attribute__((address_space(1))) unsigned int*)g,
        (__attribute__((address_space(3))) unsigned int*)l, 16, 0, 0);
}

__device__ __forceinline__ float fexp2(float x) {
#if __has_builtin(__builtin_amdgcn_exp2f)
    return __builtin_amdgcn_exp2f(x);
#else
    return exp2f(x);
#endif
}

// ---------------- fp32 -> bf16 convert ----------------
__global__ __launch_bounds__(256)
void cvt(const float* __restrict__ in, __bf16* __restrict__ out, int n) {
    int i = (blockIdx.x * 256 + threadIdx.x) * 4;
    if (i >= n) return;
    float4 v = *(const float4*)(in + i);
    bf16x4 o = { (__bf16)v.x, (__bf16)v.y, (__bf16)v.z, (__bf16)v.w };
    *(bf16x4*)(out + i) = o;
}

// ---------------- GEMM: out[m,n] = sum_k A[m,k]*W[n,k] + bias[n] ----------------
template<int MODE>
__global__ __launch_bounds__(256)
void gemm_bt(const __bf16* __restrict__ A, const __bf16* __restrict__ W,
             const float* __restrict__ bias, const float* __restrict__ hz,
             void* __restrict__ outp)
{
    __shared__ __bf16 As[128 * 32];
    __shared__ __bf16 Bs[128 * 32];
    const int tid  = threadIdx.x;
    const int lane = tid & 63, wid = tid >> 6;
    const int m0 = blockIdx.x * 128;
    const int n0 = blockIdx.y * 128;
    const int wm = (wid >> 1) * 64, wn = (wid & 1) * 64;

    f32x4 acc[4][4];
    #pragma unroll
    for (int i = 0; i < 4; i++)
        #pragma unroll
        for (int j = 0; j < 4; j++) acc[i][j] = (f32x4){0.f, 0.f, 0.f, 0.f};

    for (int kt = 0; kt < HID; kt += 32) {
        #pragma unroll
        for (int i = 0; i < 2; i++) {
            int c = wid * 128 + i * 64 + lane;
            int row = c >> 2, slot = c & 3;
            int ss = slot ^ (row & 3);
            gload16(A + (size_t)(m0 + row) * HID + kt + ss * 8, (char*)As + c * 16);
            gload16(W + (size_t)(n0 + row) * HID + kt + ss * 8, (char*)Bs + c * 16);
        }
        __syncthreads();

        bf16x8 af[4], bfr[4];
        #pragma unroll
        for (int mi = 0; mi < 4; mi++) {
            int row = wm + mi * 16 + (lane & 15);
            int off = row * 64 + (((lane >> 4) * 16) ^ ((row & 3) << 4));
            af[mi] = *(const bf16x8*)((const char*)As + off);
        }
        #pragma unroll
        for (int ni = 0; ni < 4; ni++) {
            int row = wn + ni * 16 + (lane & 15);
            int off = row * 64 + (((lane >> 4) * 16) ^ ((row & 3) << 4));
            bfr[ni] = *(const bf16x8*)((const char*)Bs + off);
        }
        #pragma unroll
        for (int mi = 0; mi < 4; mi++)
            #pragma unroll
            for (int ni = 0; ni < 4; ni++)
                acc[mi][ni] = mfma16(af[mi], bfr[ni], acc[mi][ni]);
        __syncthreads();
    }

    #pragma unroll
    for (int mi = 0; mi < 4; mi++)
        #pragma unroll
        for (int ni = 0; ni < 4; ni++)
            #pragma unroll
            for (int r = 0; r < 4; r++) {
                int m = m0 + wm + mi * 16 + ((lane >> 4) * 4) + r;
                int n = n0 + wn + ni * 16 + (lane & 15);
                float v = acc[mi][ni][r] + bias[n];
                if (MODE == 3) {
                    ((float*)outp)[(size_t)m * HID + n] = v * hz[n];
                } else {
                    int b = m >> 11, s = m & (SEQ - 1);
                    int h = n >> 6,  d = n & 63;
                    size_t idx;
                    if (MODE == 2) idx = ((size_t)(b * NH + h) * DH + d) * SEQ + s;
                    else           idx = ((size_t)(b * NH + h) * SEQ + s) * DH + d;
                    ((__bf16*)outp)[idx] = (__bf16)v;
                }
            }
}

// ---------------- flash attention, swapped-operand (q lane-local) ----------------
// grid: (S/256, NH, NB); 512 threads = 8 waves; wave w owns q-rows [w*32, w*32+32)
#define KVB 64
#define SM_SCALE 0.18033688f   // 0.125 * log2(e)

__global__ __launch_bounds__(512, 4)
void attn(const __bf16* __restrict__ Q, const __bf16* __restrict__ K,
          const __bf16* __restrict__ VT, const float* __restrict__ heads_z,
          __bf16* __restrict__ C)
{
    __shared__ __bf16 Ks[2][KVB * 64];
    __shared__ __bf16 Vs[2][KVB * 64];   // V^T tile: rows=d, cols=kv
    __shared__ __bf16 Ps[8][32 * 64];    // per-wave P, swizzled
    const int tid = threadIdx.x, lane = tid & 63, wid = tid >> 6;
    const int qb = blockIdx.x, h = blockIdx.y, b = blockIdx.z;
    const size_t bh = (size_t)(b * NH + h);
    const __bf16* Qg = Q + bh * SEQ * DH;
    const __bf16* Kg = K + bh * SEQ * DH;
    const __bf16* Vg = VT + bh * (size_t)DH * SEQ;
    const int q0 = qb * 256;

    // Q fragments (B-operand shape: col=q, k=d)
    bf16x8 qa[2][2];
    #pragma unroll
    for (int mi = 0; mi < 2; mi++)
        #pragma unroll
        for (int kf = 0; kf < 2; kf++) {
            int row = q0 + wid * 32 + mi * 16 + (lane & 15);
            qa[mi][kf] = *(const bf16x8*)(Qg + (size_t)row * DH + kf * 32 + (lane >> 4) * 8);
        }

    f32x4 ctx[2][4];   // ctx^T: col=q (lane&15), row=d
    float mrun[2] = {-1e30f, -1e30f}, lrun[2] = {0.f, 0.f};
    #pragma unroll
    for (int mi = 0; mi < 2; mi++)
        #pragma unroll
        for (int ni = 0; ni < 4; ni++) ctx[mi][ni] = (f32x4){0.f, 0.f, 0.f, 0.f};

    // stage K tile [64 kv][64 d] and V^T tile [64 d][64 kv]; 512 threads = 1 chunk each
    const int sc_row = tid >> 3, sc_slot = tid & 7;
    const int sc_ss = sc_slot ^ (sc_row & 7);

    // prologue: stage tile 0
    gload16(Kg + (size_t)sc_row * DH + sc_ss * 8, (char*)&Ks[0][0] + tid * 16);
    gload16(Vg + (size_t)sc_row * SEQ + 0 + sc_ss * 8, (char*)&Vs[0][0] + tid * 16);
    __syncthreads();

    int cur = 0;
    for (int kv0 = 0; kv0 < SEQ; kv0 += KVB) {
        // issue next-tile staging before compute (2-phase)
        if (kv0 + KVB < SEQ) {
            gload16(Kg + (size_t)(kv0 + KVB + sc_row) * DH + sc_ss * 8,
                    (char*)&Ks[cur ^ 1][0] + tid * 16);
            gload16(Vg + (size_t)sc_row * SEQ + (kv0 + KVB) + sc_ss * 8,
                    (char*)&Vs[cur ^ 1][0] + tid * 16);
        }

        // --- QK^T (swapped): st[mi][ni] = K_tile(ni) x Q(mi), col=q, row=kv ---
        bf16x8 kb[4][2];
        #pragma unroll
        for (int ni = 0; ni < 4; ni++)
            #pragma unroll
            for (int kf = 0; kf < 2; kf++) {
                int row = ni * 16 + (lane & 15);
                int off = row * 128 + ((kf * 64 + (lane >> 4) * 16) ^ ((row & 7) << 4));
                kb[ni][kf] = *(const bf16x8*)((const char*)&Ks[cur][0] + off);
            }
        f32x4 st[2][4];
        #pragma unroll
        for (int mi = 0; mi < 2; mi++)
            #pragma unroll
            for (int ni = 0; ni < 4; ni++) {
                f32x4 t = (f32x4){0.f, 0.f, 0.f, 0.f};
                t = mfma16(kb[ni][0], qa[mi][0], t);
                t = mfma16(kb[ni][1], qa[mi][1], t);
                st[mi][ni] = t;
            }

        // --- online softmax, q = lane&15 lane-local ---
        #pragma unroll
        for (int mi = 0; mi < 2; mi++) {
            float pm = st[mi][0][0];
            #pragma unroll
            for (int ni = 0; ni < 4; ni++)
                #pragma unroll
                for (int r = 0; r < 4; r++) pm = fmaxf(pm, st[mi][ni][r]);
            pm = fmaxf(pm, __shfl_xor(pm, 16));
            pm = fmaxf(pm, __shfl_xor(pm, 32));
            pm *= SM_SCALE;                        // into log2 domain
            if (!__all(pm <= mrun[mi] + 8.f)) {    // defer-max (T13)
                float nm = fmaxf(mrun[mi], pm);
                float al = fexp2(mrun[mi] - nm);
                lrun[mi] *= al;
                mrun[mi] = nm;
                #pragma unroll
                for (int ni = 0; ni < 4; ni++) ctx[mi][ni] *= al;
            }
            float rs = 0.f;
            const float mneg = -mrun[mi];
            #pragma unroll
            for (int ni = 0; ni < 4; ni++) {
                bf16x4 pb;
                #pragma unroll
                for (int r = 0; r < 4; r++) {
                    float p = fexp2(fmaf(st[mi][ni][r], SM_SCALE, mneg));
                    rs += p;
                    pb[r] = (__bf16)p;
                }
                // P^T stored as P[q][kv], swizzled, wave-private
                int row = mi * 16 + (lane & 15);
                int byte = row * 128 + ((32 * ni + 8 * (lane >> 4)) ^ ((row & 7) << 4));
                *(bf16x4*)((char*)&Ps[wid][0] + byte) = pb;
            }
            rs += __shfl_xor(rs, 16);
            rs += __shfl_xor(rs, 32);
            lrun[mi] += rs;
        }

        // --- PV (swapped): ctx^T += V^T_tile(ni) x P^T(mi) ---
        bf16x8 vb[4][2], pf[2][2];
        #pragma unroll
        for (int ni = 0; ni < 4; ni++)
            #pragma unroll
            for (int kf = 0; kf < 2; kf++) {
                int row = ni * 16 + (lane & 15);
                int off = row * 128 + ((kf * 64 + (lane >> 4) * 16) ^ ((row & 7) << 4));
                vb[ni][kf] = *(const bf16x8*)((const char*)&Vs[cur][0] + off);
            }
        #pragma unroll
        for (int mi = 0; mi < 2; mi++)
            #pragma unroll
            for (int kf = 0; kf < 2; kf++) {
                int row = mi * 16 + (lane & 15);
                int byte = row * 128 + ((16 * (lane >> 4) + 64 * kf) ^ ((row & 7) << 4));
                pf[mi][kf] = *(const bf16x8*)((const char*)&Ps[wid][0] + byte);
            }
        #pragma unroll
        for (int mi = 0; mi < 2; mi++)
            #pragma unroll
            for (int ni = 0; ni < 4; ni++) {
                ctx[mi][ni] = mfma16(vb[ni][0], pf[mi][0], ctx[mi][ni]);
                ctx[mi][ni] = mfma16(vb[ni][1], pf[mi][1], ctx[mi][ni]);
            }

        __syncthreads();   // next tile staged + everyone done with cur
        cur ^= 1;
    }

    // epilogue: out[q][d] = ctx^T * hz / l ; pack 4 consecutive d
    const float hzv = heads_z[h];
    #pragma unroll
    for (int mi = 0; mi < 2; mi++) {
        float rl = hzv / lrun[mi];
        int q = q0 + wid * 32 + mi * 16 + (lane & 15);
        #pragma unroll
        for (int ni = 0; ni < 4; ni++) {
            bf16x4 o;
            #pragma unroll
            for (int r = 0; r < 4; r++) o[r] = (__bf16)(ctx[mi][ni][r] * rl);
            int d = ni * 16 + (lane >> 4) * 4;
            *(bf16x4*)(C + (size_t)(b * SEQ + q) * HID + h * DH + d) = o;
        }
    }
}

extern "C" void kernel_launch(void* const* d_in, const int* in_sizes, int n_in,
                              void* d_out, int out_size, void* d_ws, size_t ws_size,
                              hipStream_t stream)
{
    const float* X    = (const float*)d_in[0];
    const float* Wq   = (const float*)d_in[1];
    const float* bq   = (const float*)d_in[2];
    const float* Wk   = (const float*)d_in[3];
    const float* bk   = (const float*)d_in[4];
    const float* Wv   = (const float*)d_in[5];
    const float* bv   = (const float*)d_in[6];
    const float* Wp   = (const float*)d_in[7];
    const float* bp   = (const float*)d_in[8];
    const float* hz   = (const float*)d_in[9];
    const float* hidz = (const float*)d_in[10];

    __bf16* ws  = (__bf16*)d_ws;
    __bf16* Xb  = ws;
    __bf16* Wqb = Xb  + (size_t)MTOT * HID;
    __bf16* Wkb = Wqb + (size_t)HID * HID;
    __bf16* Wvb = Wkb + (size_t)HID * HID;
    __bf16* Wpb = Wvb + (size_t)HID * HID;
    __bf16* Qb  = Wpb + (size_t)HID * HID;
    __bf16* Kb  = Qb  + (size_t)MTOT * HID;
    __bf16* VTb = Kb  + (size_t)MTOT * HID;
    __bf16* Cb  = VTb + (size_t)MTOT * HID;

    cvt<<<(MTOT * HID / 4 + 255) / 256, 256, 0, stream>>>(X,  Xb,  MTOT * HID);
    cvt<<<(HID * HID / 4 + 255) / 256, 256, 0, stream>>>(Wq, Wqb, HID * HID);
    cvt<<<(HID * HID / 4 + 255) / 256, 256, 0, stream>>>(Wk, Wkb, HID * HID);
    cvt<<<(HID * HID / 4 + 255) / 256, 256, 0, stream>>>(Wv, Wvb, HID * HID);
    cvt<<<(HID * HID / 4 + 255) / 256, 256, 0, stream>>>(Wp, Wpb, HID * HID);

    dim3 gg(MTOT / 128, HID / 128);
    gemm_bt<0><<<gg, 256, 0, stream>>>(Xb, Wqb, bq, nullptr, Qb);
    gemm_bt<1><<<gg, 256, 0, stream>>>(Xb, Wkb, bk, nullptr, Kb);
    gemm_bt<2><<<gg, 256, 0, stream>>>(Xb, Wvb, bv, nullptr, VTb);

    attn<<<dim3(SEQ / 256, NH, NB), 512, 0, stream>>>(Qb, Kb, VTb, hz, Cb);

    gemm_bt<3><<<gg, 256, 0, stream>>>(Cb, Wpb, bp, hidz, d_out);
}

// Round 3
// 220.322 us; speedup vs baseline: 1.5351x; 1.0026x over previous
//
#include <hip/hip_runtime.h>
#include <hip/hip_bf16.h>

#define HID 1024
#define NH 16
#define DH 64
#define SEQ 2048
#define NB 4
#define MTOT (NB*SEQ)   // 8192

typedef __attribute__((ext_vector_type(4))) float f32x4;
typedef __attribute__((ext_vector_type(16))) float f32x16;
typedef __attribute__((ext_vector_type(8))) __bf16 bf16x8;
typedef __attribute__((ext_vector_type(4))) __bf16 bf16x4;
typedef __attribute__((ext_vector_type(2))) __bf16 bf16x2;
typedef __attribute__((ext_vector_type(2))) int i32x2;

__device__ __forceinline__ f32x4 mfma16(bf16x8 a, bf16x8 b, f32x4 c) {
    return __builtin_amdgcn_mfma_f32_16x16x32_bf16(a, b, c, 0, 0, 0);
}
__device__ __forceinline__ f32x16 mfma32(bf16x8 a, bf16x8 b, f32x16 c) {
    return __builtin_amdgcn_mfma_f32_32x32x16_bf16(a, b, c, 0, 0, 0);
}

__device__ __forceinline__ void gload16(const void* g, void* l) {
    __builtin_amdgcn_global_load_lds(
        (const __attribute__((address_space(1))) unsigned int*)g,
        (__attribute__((address_space(3))) unsigned int*)l, 16, 0, 0);
}

__device__ __forceinline__ float fexp2(float x) {
#if __has_builtin(__builtin_amdgcn_exp2f)
    return __builtin_amdgcn_exp2f(x);
#else
    return exp2f(x);
#endif
}

__device__ __forceinline__ unsigned pkbf2(float lo, float hi) {
    union { bf16x2 v; unsigned u; } c;
    c.v = (bf16x2){ (__bf16)lo, (__bf16)hi };
    return c.u;
}

// exchange across the lane32 boundary: on return a = (lh?b_from_partner:a_self),
// b = (lh?b_self:a_from_partner)  -- i.e. v_permlane32_swap semantics.
__device__ __forceinline__ void swap32(unsigned &a, unsigned &b) {
#if __has_builtin(__builtin_amdgcn_permlane32_swap)
    i32x2 r = __builtin_amdgcn_permlane32_swap((int)a, (int)b, false, false);
    a = (unsigned)r.x; b = (unsigned)r.y;
#else
    const bool hi = (threadIdx.x & 32) != 0;
    unsigned ta = __shfl_xor(a, 32), tb = __shfl_xor(b, 32);
    unsigned na = hi ? tb : a;
    unsigned nb = hi ? b : ta;
    a = na; b = nb;
#endif
}

__device__ __forceinline__ float swapmaxf(float x) {
    unsigned a = __float_as_uint(x), b = a;
    swap32(a, b);
    return fmaxf(__uint_as_float(a), __uint_as_float(b));
}
__device__ __forceinline__ float swapaddf(float x) {
    unsigned a = __float_as_uint(x), b = a;
    swap32(a, b);
    return __uint_as_float(a) + __uint_as_float(b);
}

// ---------------- fp32 -> bf16 convert ----------------
__global__ __launch_bounds__(256)
void cvt(const float* __restrict__ in, __bf16* __restrict__ out, int n) {
    int i = (blockIdx.x * 256 + threadIdx.x) * 4;
    if (i >= n) return;
    float4 v = *(const float4*)(in + i);
    bf16x4 o = { (__bf16)v.x, (__bf16)v.y, (__bf16)v.z, (__bf16)v.w };
    *(bf16x4*)(out + i) = o;
}

// ---------------- GEMM: out[m,n] = sum_k A[m,k]*W[n,k] + bias[n] ----------------
template<int MODE>
__global__ __launch_bounds__(256)
void gemm_bt(const __bf16* __restrict__ A, const __bf16* __restrict__ W,
             const float* __restrict__ bias, const float* __restrict__ hz,
             void* __restrict__ outp)
{
    __shared__ __bf16 As[128 * 32];
    __shared__ __bf16 Bs[128 * 32];
    const int tid  = threadIdx.x;
    const int lane = tid & 63, wid = tid >> 6;
    const int m0 = blockIdx.x * 128;
    const int n0 = blockIdx.y * 128;
    const int wm = (wid >> 1) * 64, wn = (wid & 1) * 64;

    f32x4 acc[4][4];
    #pragma unroll
    for (int i = 0; i < 4; i++)
        #pragma unroll
        for (int j = 0; j < 4; j++) acc[i][j] = (f32x4){0.f, 0.f, 0.f, 0.f};

    for (int kt = 0; kt < HID; kt += 32) {
        #pragma unroll
        for (int i = 0; i < 2; i++) {
            int c = wid * 128 + i * 64 + lane;
            int row = c >> 2, slot = c & 3;
            int ss = slot ^ (row & 3);
            gload16(A + (size_t)(m0 + row) * HID + kt + ss * 8, (char*)As + c * 16);
            gload16(W + (size_t)(n0 + row) * HID + kt + ss * 8, (char*)Bs + c * 16);
        }
        __syncthreads();

        bf16x8 af[4], bfr[4];
        #pragma unroll
        for (int mi = 0; mi < 4; mi++) {
            int row = wm + mi * 16 + (lane & 15);
            int off = row * 64 + (((lane >> 4) * 16) ^ ((row & 3) << 4));
            af[mi] = *(const bf16x8*)((const char*)As + off);
        }
        #pragma unroll
        for (int ni = 0; ni < 4; ni++) {
            int row = wn + ni * 16 + (lane & 15);
            int off = row * 64 + (((lane >> 4) * 16) ^ ((row & 3) << 4));
            bfr[ni] = *(const bf16x8*)((const char*)Bs + off);
        }
        #pragma unroll
        for (int mi = 0; mi < 4; mi++)
            #pragma unroll
            for (int ni = 0; ni < 4; ni++)
                acc[mi][ni] = mfma16(af[mi], bfr[ni], acc[mi][ni]);
        __syncthreads();
    }

    #pragma unroll
    for (int mi = 0; mi < 4; mi++)
        #pragma unroll
        for (int ni = 0; ni < 4; ni++)
            #pragma unroll
            for (int r = 0; r < 4; r++) {
                int m = m0 + wm + mi * 16 + ((lane >> 4) * 4) + r;
                int n = n0 + wn + ni * 16 + (lane & 15);
                float v = acc[mi][ni][r] + bias[n];
                if (MODE == 3) {
                    ((float*)outp)[(size_t)m * HID + n] = v * hz[n];
                } else {
                    int b = m >> 11, s = m & (SEQ - 1);
                    int h = n >> 6,  d = n & 63;
                    size_t idx;
                    if (MODE == 2) idx = ((size_t)(b * NH + h) * DH + d) * SEQ + s;
                    else           idx = ((size_t)(b * NH + h) * SEQ + s) * DH + d;
                    ((__bf16*)outp)[idx] = (__bf16)v;
                }
            }
}

// ---------------- flash attention: 32x32 MFMA, in-register softmax ----------------
// grid: (S/256, NH, NB); 512 threads = 8 waves; wave w owns q-rows [w*32, w*32+32)
// Swapped operands: S^T = mfma(K, Q) so q = lane&31 is lane-local.
#define KVB 64
#define SM_SCALE 0.18033688f   // 0.125 * log2(e)

__global__ __launch_bounds__(512, 4)
void attn(const __bf16* __restrict__ Q, const __bf16* __restrict__ K,
          const __bf16* __restrict__ VT, const float* __restrict__ heads_z,
          __bf16* __restrict__ C)
{
    __shared__ __bf16 Ks[2][KVB * 64];
    __shared__ __bf16 Vs[2][KVB * 64];   // V^T tile: rows=d, cols=kv
    const int tid = threadIdx.x, lane = tid & 63, wid = tid >> 6;
    const int lh = lane >> 5;            // lane-half (0/1)
    const int qb = blockIdx.x, hd = blockIdx.y, b = blockIdx.z;
    const size_t bh = (size_t)(b * NH + hd);
    const __bf16* Qg = Q + bh * SEQ * DH;
    const __bf16* Kg = K + bh * SEQ * DH;
    const __bf16* Vg = VT + bh * (size_t)DH * SEQ;
    const int q0 = qb * 256;
    const int q = q0 + wid * 32 + (lane & 31);

    // Q B-fragments: qf[s] = Q[q][16s + 8*lh .. +7]
    bf16x8 qf[4];
    #pragma unroll
    for (int s = 0; s < 4; s++)
        qf[s] = *(const bf16x8*)(Qg + (size_t)q * DH + s * 16 + lh * 8);

    f32x16 ctx0, ctx1;   // ctx^T: col=q, rows d=0..31 (ctx0), 32..63 (ctx1)
    #pragma unroll
    for (int r = 0; r < 16; r++) { ctx0[r] = 0.f; ctx1[r] = 0.f; }
    float mrun = -1e30f, lrun = 0.f;

    // staging map (same involution both sides)
    const int sc_row = tid >> 3, sc_slot = tid & 7;
    const int sc_ss = sc_slot ^ (sc_row & 7);

    gload16(Kg + (size_t)sc_row * DH + sc_ss * 8, (char*)&Ks[0][0] + tid * 16);
    gload16(Vg + (size_t)sc_row * SEQ + 0 + sc_ss * 8, (char*)&Vs[0][0] + tid * 16);
    __syncthreads();

    int cur = 0;
    for (int kv0 = 0; kv0 < SEQ; kv0 += KVB) {
        if (kv0 + KVB < SEQ) {
            gload16(Kg + (size_t)(kv0 + KVB + sc_row) * DH + sc_ss * 8,
                    (char*)&Ks[cur ^ 1][0] + tid * 16);
            gload16(Vg + (size_t)sc_row * SEQ + (kv0 + KVB) + sc_ss * 8,
                    (char*)&Vs[cur ^ 1][0] + tid * 16);
        }

        // --- QK^T: st[kv][q], two kv-subtiles of 32 ---
        f32x16 st0, st1;
        #pragma unroll
        for (int r = 0; r < 16; r++) { st0[r] = 0.f; st1[r] = 0.f; }
        const char* Kb = (const char*)&Ks[cur][0];
        __builtin_amdgcn_s_setprio(1);
        #pragma unroll
        for (int s = 0; s < 4; s++) {
            int r0 = lane & 31, r1 = r0 + 32;
            int slot = 2 * s + lh;
            bf16x8 k0 = *(const bf16x8*)(Kb + r0 * 128 + ((slot ^ (r0 & 7)) << 4));
            bf16x8 k1 = *(const bf16x8*)(Kb + r1 * 128 + ((slot ^ (r1 & 7)) << 4));
            st0 = mfma32(k0, qf[s], st0);
            st1 = mfma32(k1, qf[s], st1);
        }
        __builtin_amdgcn_s_setprio(0);

        // --- online softmax, fully in-register ---
        float pm = st0[0];
        #pragma unroll
        for (int r = 1; r < 16; r++) pm = fmaxf(pm, st0[r]);
        #pragma unroll
        for (int r = 0; r < 16; r++) pm = fmaxf(pm, st1[r]);
        pm = swapmaxf(pm);
        pm *= SM_SCALE;
        if (!__all(pm <= mrun + 8.f)) {      // defer-max (T13)
            float nm = fmaxf(mrun, pm);
            float al = fexp2(mrun - nm);
            lrun *= al; mrun = nm;
            #pragma unroll
            for (int r = 0; r < 16; r++) { ctx0[r] *= al; ctx1[r] *= al; }
        }
        float rs = 0.f;
        const float mneg = -mrun;
        #pragma unroll
        for (int r = 0; r < 16; r++) {
            float e0 = fexp2(fmaf(st0[r], SM_SCALE, mneg));
            float e1 = fexp2(fmaf(st1[r], SM_SCALE, mneg));
            st0[r] = e0; st1[r] = e1;
            rs += e0 + e1;
        }
        lrun += swapaddf(rs);

        // --- P -> PV B-fragments, in-register (T12 exchange) ---
        unsigned X0 = pkbf2(st0[0],  st0[1]),  X1 = pkbf2(st0[2],  st0[3]);
        unsigned X2 = pkbf2(st0[4],  st0[5]),  X3 = pkbf2(st0[6],  st0[7]);
        unsigned X4 = pkbf2(st0[8],  st0[9]),  X5 = pkbf2(st0[10], st0[11]);
        unsigned X6 = pkbf2(st0[12], st0[13]), X7 = pkbf2(st0[14], st0[15]);
        unsigned Y0 = pkbf2(st1[0],  st1[1]),  Y1 = pkbf2(st1[2],  st1[3]);
        unsigned Y2 = pkbf2(st1[4],  st1[5]),  Y3 = pkbf2(st1[6],  st1[7]);
        unsigned Y4 = pkbf2(st1[8],  st1[9]),  Y5 = pkbf2(st1[10], st1[11]);
        unsigned Y6 = pkbf2(st1[12], st1[13]), Y7 = pkbf2(st1[14], st1[15]);
        swap32(X0, X2); swap32(X1, X3);   // pf[0] = {X0,X1,X2,X3}
        swap32(X4, X6); swap32(X5, X7);   // pf[1]
        swap32(Y0, Y2); swap32(Y1, Y3);   // pf[2]
        swap32(Y4, Y6); swap32(Y5, Y7);   // pf[3]
        union W4 { unsigned w[4]; bf16x8 v; };
        W4 pf[4];
        pf[0].w[0]=X0; pf[0].w[1]=X1; pf[0].w[2]=X2; pf[0].w[3]=X3;
        pf[1].w[0]=X4; pf[1].w[1]=X5; pf[1].w[2]=X6; pf[1].w[3]=X7;
        pf[2].w[0]=Y0; pf[2].w[1]=Y1; pf[2].w[2]=Y2; pf[2].w[3]=Y3;
        pf[3].w[0]=Y4; pf[3].w[1]=Y5; pf[3].w[2]=Y6; pf[3].w[3]=Y7;

        // --- PV: ctx^T += V^T x P^T ---
        const char* Vb = (const char*)&Vs[cur][0];
        __builtin_amdgcn_s_setprio(1);
        #pragma unroll
        for (int s = 0; s < 4; s++) {
            int r0 = lane & 31, r1 = r0 + 32;
            int slot = 2 * s + lh;
            bf16x8 v0 = *(const bf16x8*)(Vb + r0 * 128 + ((slot ^ (r0 & 7)) << 4));
            bf16x8 v1 = *(const bf16x8*)(Vb + r1 * 128 + ((slot ^ (r1 & 7)) << 4));
            ctx0 = mfma32(v0, pf[s].v, ctx0);
            ctx1 = mfma32(v1, pf[s].v, ctx1);
        }
        __builtin_amdgcn_s_setprio(0);

        __syncthreads();
        cur ^= 1;
    }

    // epilogue: out[q][d] = ctx^T * hz / l
    const float hzv = heads_z[hd];
    const float rl = hzv / lrun;
    __bf16* Crow = C + (size_t)(b * SEQ + q) * HID + hd * DH;
    #pragma unroll
    for (int g = 0; g < 4; g++) {
        bf16x4 o0, o1;
        #pragma unroll
        for (int j = 0; j < 4; j++) {
            o0[j] = (__bf16)(ctx0[4 * g + j] * rl);
            o1[j] = (__bf16)(ctx1[4 * g + j] * rl);
        }
        int d0 = 8 * g + 4 * lh;
        *(bf16x4*)(Crow + d0) = o0;
        *(bf16x4*)(Crow + 32 + d0) = o1;
    }
}

extern "C" void kernel_launch(void* const* d_in, const int* in_sizes, int n_in,
                              void* d_out, int out_size, void* d_ws, size_t ws_size,
                              hipStream_t stream)
{
    const float* X    = (const float*)d_in[0];
    const float* Wq   = (const float*)d_in[1];
    const float* bq   = (const float*)d_in[2];
    const float* Wk   = (const float*)d_in[3];
    const float* bk   = (const float*)d_in[4];
    const float* Wv   = (const float*)d_in[5];
    const float* bv   = (const float*)d_in[6];
    const float* Wp   = (const float*)d_in[7];
    const float* bp   = (const float*)d_in[8];
    const float* hz   = (const float*)d_in[9];
    const float* hidz = (const float*)d_in[10];

    __bf16* ws  = (__bf16*)d_ws;
    __bf16* Xb  = ws;
    __bf16* Wqb = Xb  + (size_t)MTOT * HID;
    __bf16* Wkb = Wqb + (size_t)HID * HID;
    __bf16* Wvb = Wkb + (size_t)HID * HID;
    __bf16* Wpb = Wvb + (size_t)HID * HID;
    __bf16* Qb  = Wpb + (size_t)HID * HID;
    __bf16* Kb  = Qb  + (size_t)MTOT * HID;
    __bf16* VTb = Kb  + (size_t)MTOT * HID;
    __bf16* Cb  = VTb + (size_t)MTOT * HID;

    cvt<<<(MTOT * HID / 4 + 255) / 256, 256, 0, stream>>>(X,  Xb,  MTOT * HID);
    cvt<<<(HID * HID / 4 + 255) / 256, 256, 0, stream>>>(Wq, Wqb, HID * HID);
    cvt<<<(HID * HID / 4 + 255) / 256, 256, 0, stream>>>(Wk, Wkb, HID * HID);
    cvt<<<(HID * HID / 4 + 255) / 256, 256, 0, stream>>>(Wv, Wvb, HID * HID);
    cvt<<<(HID * HID / 4 + 255) / 256, 256, 0, stream>>>(Wp, Wpb, HID * HID);

    dim3 gg(MTOT / 128, HID / 128);
    gemm_bt<0><<<gg, 256, 0, stream>>>(Xb, Wqb, bq, nullptr, Qb);
    gemm_bt<1><<<gg, 256, 0, stream>>>(Xb, Wkb, bk, nullptr, Kb);
    gemm_bt<2><<<gg, 256, 0, stream>>>(Xb, Wvb, bv, nullptr, VTb);

    attn<<<dim3(SEQ / 256, NH, NB), 512, 0, stream>>>(Qb, Kb, VTb, hz, Cb);

    gemm_bt<3><<<gg, 256, 0, stream>>>(Cb, Wpb, bp, hidz, d_out);
}

// Round 4
// 209.660 us; speedup vs baseline: 1.6131x; 1.0509x over previous
//
#include <hip/hip_runtime.h>
#include <hip/hip_bf16.h>

#define HID 1024
#define NH 16
#define DH 64
#define SEQ 2048
#define NB 4
#define MTOT (NB*SEQ)   // 8192

typedef __attribute__((ext_vector_type(4))) float f32x4;
typedef __attribute__((ext_vector_type(16))) float f32x16;
typedef __attribute__((ext_vector_type(8))) __bf16 bf16x8;
typedef __attribute__((ext_vector_type(4))) __bf16 bf16x4;
typedef __attribute__((ext_vector_type(2))) __bf16 bf16x2;
typedef __attribute__((ext_vector_type(2))) int i32x2;

__device__ __forceinline__ f32x4 mfma16(bf16x8 a, bf16x8 b, f32x4 c) {
    return __builtin_amdgcn_mfma_f32_16x16x32_bf16(a, b, c, 0, 0, 0);
}
__device__ __forceinline__ f32x16 mfma32(bf16x8 a, bf16x8 b, f32x16 c) {
    return __builtin_amdgcn_mfma_f32_32x32x16_bf16(a, b, c, 0, 0, 0);
}

__device__ __forceinline__ void gload16(const void* g, void* l) {
    __builtin_amdgcn_global_load_lds(
        (const __attribute__((address_space(1))) unsigned int*)g,
        (__attribute__((address_space(3))) unsigned int*)l, 16, 0, 0);
}

__device__ __forceinline__ float fexp2(float x) {
#if __has_builtin(__builtin_amdgcn_exp2f)
    return __builtin_amdgcn_exp2f(x);
#else
    return exp2f(x);
#endif
}

__device__ __forceinline__ unsigned pkbf2(float lo, float hi) {
    union { bf16x2 v; unsigned u; } c;
    c.v = (bf16x2){ (__bf16)lo, (__bf16)hi };
    return c.u;
}

// v_permlane32_swap semantics across the lane32 boundary.
__device__ __forceinline__ void swap32(unsigned &a, unsigned &b) {
#if __has_builtin(__builtin_amdgcn_permlane32_swap)
    i32x2 r = __builtin_amdgcn_permlane32_swap((int)a, (int)b, false, false);
    a = (unsigned)r.x; b = (unsigned)r.y;
#else
    const bool hi = (threadIdx.x & 32) != 0;
    unsigned ta = __shfl_xor(a, 32), tb = __shfl_xor(b, 32);
    unsigned na = hi ? tb : a;
    unsigned nb = hi ? b : ta;
    a = na; b = nb;
#endif
}

__device__ __forceinline__ float swapmaxf(float x) {
    unsigned a = __float_as_uint(x), b = a;
    swap32(a, b);
    return fmaxf(__uint_as_float(a), __uint_as_float(b));
}
__device__ __forceinline__ float swapaddf(float x) {
    unsigned a = __float_as_uint(x), b = a;
    swap32(a, b);
    return __uint_as_float(a) + __uint_as_float(b);
}

// ---------------- fused fp32 -> bf16 convert (one launch, grid.y selects tensor) --------
__global__ __launch_bounds__(256)
void cvt5(const float* __restrict__ X,  const float* __restrict__ Wq,
          const float* __restrict__ Wk, const float* __restrict__ Wv,
          const float* __restrict__ Wp,
          __bf16* __restrict__ Xb,  __bf16* __restrict__ Wqb,
          __bf16* __restrict__ Wkb, __bf16* __restrict__ Wvb,
          __bf16* __restrict__ Wpb)
{
    const float* src; __bf16* dst; int n;
    switch (blockIdx.y) {
        case 0:  src = X;  dst = Xb;  n = MTOT * HID; break;
        case 1:  src = Wq; dst = Wqb; n = HID * HID;  break;
        case 2:  src = Wk; dst = Wkb; n = HID * HID;  break;
        case 3:  src = Wv; dst = Wvb; n = HID * HID;  break;
        default: src = Wp; dst = Wpb; n = HID * HID;  break;
    }
    const int stride = gridDim.x * 256 * 4;
    for (int i = (blockIdx.x * 256 + threadIdx.x) * 4; i < n; i += stride) {
        float4 v = *(const float4*)(src + i);
        bf16x4 o = { (__bf16)v.x, (__bf16)v.y, (__bf16)v.z, (__bf16)v.w };
        *(bf16x4*)(dst + i) = o;
    }
}

// ---------------- QKV GEMM (one launch; grid.z = mode 0:Q 1:K 2:V) ----------------
// out[m,n] = sum_k A[m,k]*W[n,k] + bias[n];  Q/K -> [B,H,S,D] bf16, V -> [B,H,D,S] bf16
__global__ __launch_bounds__(256)
void gemm_qkv(const __bf16* __restrict__ A,
              const __bf16* __restrict__ Wq, const __bf16* __restrict__ Wk,
              const __bf16* __restrict__ Wv,
              const float* __restrict__ bq, const float* __restrict__ bk,
              const float* __restrict__ bv,
              __bf16* __restrict__ Qo, __bf16* __restrict__ Ko, __bf16* __restrict__ Vo)
{
    __shared__ __bf16 As[128 * 32];
    __shared__ __bf16 Bs[128 * 32];
    const int mode = blockIdx.z;
    const __bf16* W    = mode == 0 ? Wq : mode == 1 ? Wk : Wv;
    const float*  bias = mode == 0 ? bq : mode == 1 ? bk : bv;
    __bf16*       Og   = mode == 0 ? Qo : mode == 1 ? Ko : Vo;

    const int tid  = threadIdx.x;
    const int lane = tid & 63, wid = tid >> 6;
    const int m0 = blockIdx.x * 128;
    const int n0 = blockIdx.y * 128;
    const int wm = (wid >> 1) * 64, wn = (wid & 1) * 64;

    f32x4 acc[4][4];
    #pragma unroll
    for (int i = 0; i < 4; i++)
        #pragma unroll
        for (int j = 0; j < 4; j++) acc[i][j] = (f32x4){0.f, 0.f, 0.f, 0.f};

    for (int kt = 0; kt < HID; kt += 32) {
        #pragma unroll
        for (int i = 0; i < 2; i++) {
            int c = wid * 128 + i * 64 + lane;
            int row = c >> 2, slot = c & 3;
            int ss = slot ^ (row & 3);
            gload16(A + (size_t)(m0 + row) * HID + kt + ss * 8, (char*)As + c * 16);
            gload16(W + (size_t)(n0 + row) * HID + kt + ss * 8, (char*)Bs + c * 16);
        }
        __syncthreads();

        bf16x8 af[4], bfr[4];
        #pragma unroll
        for (int mi = 0; mi < 4; mi++) {
            int row = wm + mi * 16 + (lane & 15);
            int off = row * 64 + (((lane >> 4) * 16) ^ ((row & 3) << 4));
            af[mi] = *(const bf16x8*)((const char*)As + off);
        }
        #pragma unroll
        for (int ni = 0; ni < 4; ni++) {
            int row = wn + ni * 16 + (lane & 15);
            int off = row * 64 + (((lane >> 4) * 16) ^ ((row & 3) << 4));
            bfr[ni] = *(const bf16x8*)((const char*)Bs + off);
        }
        #pragma unroll
        for (int mi = 0; mi < 4; mi++)
            #pragma unroll
            for (int ni = 0; ni < 4; ni++)
                acc[mi][ni] = mfma16(af[mi], bfr[ni], acc[mi][ni]);
        __syncthreads();
    }

    #pragma unroll
    for (int mi = 0; mi < 4; mi++)
        #pragma unroll
        for (int ni = 0; ni < 4; ni++)
            #pragma unroll
            for (int r = 0; r < 4; r++) {
                int m = m0 + wm + mi * 16 + ((lane >> 4) * 4) + r;
                int n = n0 + wn + ni * 16 + (lane & 15);
                float v = acc[mi][ni][r] + bias[n];
                int b = m >> 11, s = m & (SEQ - 1);
                int h = n >> 6,  d = n & 63;
                size_t idx;
                if (mode == 2) idx = ((size_t)(b * NH + h) * DH + d) * SEQ + s;
                else           idx = ((size_t)(b * NH + h) * SEQ + s) * DH + d;
                Og[idx] = (__bf16)v;
            }
}

// ---------------- proj GEMM: out fp32 = (A W^T + bias) * hidden_z ----------------
__global__ __launch_bounds__(256)
void gemm_proj(const __bf16* __restrict__ A, const __bf16* __restrict__ W,
               const float* __restrict__ bias, const float* __restrict__ hz,
               float* __restrict__ outp)
{
    __shared__ __bf16 As[128 * 32];
    __shared__ __bf16 Bs[128 * 32];
    const int tid  = threadIdx.x;
    const int lane = tid & 63, wid = tid >> 6;
    const int m0 = blockIdx.x * 128;
    const int n0 = blockIdx.y * 128;
    const int wm = (wid >> 1) * 64, wn = (wid & 1) * 64;

    f32x4 acc[4][4];
    #pragma unroll
    for (int i = 0; i < 4; i++)
        #pragma unroll
        for (int j = 0; j < 4; j++) acc[i][j] = (f32x4){0.f, 0.f, 0.f, 0.f};

    for (int kt = 0; kt < HID; kt += 32) {
        #pragma unroll
        for (int i = 0; i < 2; i++) {
            int c = wid * 128 + i * 64 + lane;
            int row = c >> 2, slot = c & 3;
            int ss = slot ^ (row & 3);
            gload16(A + (size_t)(m0 + row) * HID + kt + ss * 8, (char*)As + c * 16);
            gload16(W + (size_t)(n0 + row) * HID + kt + ss * 8, (char*)Bs + c * 16);
        }
        __syncthreads();

        bf16x8 af[4], bfr[4];
        #pragma unroll
        for (int mi = 0; mi < 4; mi++) {
            int row = wm + mi * 16 + (lane & 15);
            int off = row * 64 + (((lane >> 4) * 16) ^ ((row & 3) << 4));
            af[mi] = *(const bf16x8*)((const char*)As + off);
        }
        #pragma unroll
        for (int ni = 0; ni < 4; ni++) {
            int row = wn + ni * 16 + (lane & 15);
            int off = row * 64 + (((lane >> 4) * 16) ^ ((row & 3) << 4));
            bfr[ni] = *(const bf16x8*)((const char*)Bs + off);
        }
        #pragma unroll
        for (int mi = 0; mi < 4; mi++)
            #pragma unroll
            for (int ni = 0; ni < 4; ni++)
                acc[mi][ni] = mfma16(af[mi], bfr[ni], acc[mi][ni]);
        __syncthreads();
    }

    #pragma unroll
    for (int mi = 0; mi < 4; mi++)
        #pragma unroll
        for (int ni = 0; ni < 4; ni++)
            #pragma unroll
            for (int r = 0; r < 4; r++) {
                int m = m0 + wm + mi * 16 + ((lane >> 4) * 4) + r;
                int n = n0 + wn + ni * 16 + (lane & 15);
                outp[(size_t)m * HID + n] = (acc[mi][ni][r] + bias[n]) * hz[n];
            }
}

// ---------------- flash attention: 32x32 MFMA, KVB=128, XCD-local K/V ----------------
// 1D grid 512 blocks; id&7 = XCD slot; all 8 q-blocks of a (b,h) share one XCD.
#define KVB 128
#define SM_SCALE 0.18033688f   // 0.125 * log2(e)

__global__ __launch_bounds__(512, 4)
void attn(const __bf16* __restrict__ Q, const __bf16* __restrict__ K,
          const __bf16* __restrict__ VT, const float* __restrict__ heads_z,
          __bf16* __restrict__ C)
{
    __shared__ __bf16 Ks[2][KVB * 64];   // [kv][64 d]   rows 128 B
    __shared__ __bf16 Vs[2][64 * KVB];   // [d][128 kv]  rows 256 B
    const int tid = threadIdx.x, lane = tid & 63, wid = tid >> 6;
    const int lh = lane >> 5;
    const int id = blockIdx.x;
    const int bh = (id & 7) | ((id >> 6) << 3);   // bijective: bh&7 = id&7 -> same XCD
    const int qb = (id >> 3) & 7;
    const int b = bh >> 4, hd = bh & 15;
    const __bf16* Qg = Q + (size_t)bh * SEQ * DH;
    const __bf16* Kg = K + (size_t)bh * SEQ * DH;
    const __bf16* Vg = VT + (size_t)bh * DH * SEQ;
    const int q = qb * 256 + wid * 32 + (lane & 31);
    const int r0 = lane & 31;
    const int kx = (r0 & 7) << 4;    // K row-XOR (128B rows); (r0+32)&7 == r0&7
    const int vx = (r0 & 15) << 4;   // V row-XOR (256B rows); (r0+32)&15 == r0&15

    // Q B-fragments: qf[s] = Q[q][16s + 8*lh .. +7]
    bf16x8 qf[4];
    #pragma unroll
    for (int s = 0; s < 4; s++)
        qf[s] = *(const bf16x8*)(Qg + (size_t)q * DH + s * 16 + lh * 8);

    f32x16 ctx0, ctx1;   // ctx^T: col=q, rows d=0..31 (ctx0), 32..63 (ctx1)
    #pragma unroll
    for (int r = 0; r < 16; r++) { ctx0[r] = 0.f; ctx1[r] = 0.f; }
    float mrun = -1e30f, lrun = 0.f;

    // staging: K tile 1024 chunks (c: row=c>>3, slot=c&7), V tile 1024 chunks
    // (c: row=c>>4, slot=c&15); thread t stages chunks t and t+512 of each.
    const int kr0 = tid >> 3,          ksl0 = tid & 7,          kss0 = ksl0 ^ (kr0 & 7);
    const int kr1 = (tid + 512) >> 3,  ksl1 = tid & 7,          kss1 = ksl1 ^ (kr1 & 7);
    const int vr0 = tid >> 4,          vsl0 = tid & 15,         vss0 = vsl0 ^ (vr0 & 15);
    const int vr1 = (tid + 512) >> 4,  vsl1 = tid & 15,         vss1 = vsl1 ^ (vr1 & 15);

    {
        gload16(Kg + (size_t)kr0 * DH + kss0 * 8, (char*)&Ks[0][0] + tid * 16);
        gload16(Kg + (size_t)kr1 * DH + kss1 * 8, (char*)&Ks[0][0] + (tid + 512) * 16);
        gload16(Vg + (size_t)vr0 * SEQ + 0 + vss0 * 8, (char*)&Vs[0][0] + tid * 16);
        gload16(Vg + (size_t)vr1 * SEQ + 0 + vss1 * 8, (char*)&Vs[0][0] + (tid + 512) * 16);
    }
    __syncthreads();

    int cur = 0;
    for (int kv0 = 0; kv0 < SEQ; kv0 += KVB) {
        if (kv0 + KVB < SEQ) {
            int nx = kv0 + KVB;
            gload16(Kg + (size_t)(nx + kr0) * DH + kss0 * 8, (char*)&Ks[cur ^ 1][0] + tid * 16);
            gload16(Kg + (size_t)(nx + kr1) * DH + kss1 * 8, (char*)&Ks[cur ^ 1][0] + (tid + 512) * 16);
            gload16(Vg + (size_t)vr0 * SEQ + nx + vss0 * 8, (char*)&Vs[cur ^ 1][0] + tid * 16);
            gload16(Vg + (size_t)vr1 * SEQ + nx + vss1 * 8, (char*)&Vs[cur ^ 1][0] + (tid + 512) * 16);
        }

        #pragma unroll
        for (int hh = 0; hh < 2; hh++) {          // two 64-wide kv halves
            const char* Kb = (const char*)&Ks[cur][0] + hh * 64 * 128;
            const char* Vb = (const char*)&Vs[cur][0];

            // --- QK^T: st[kv][q] ---
            f32x16 st0, st1;
            #pragma unroll
            for (int r = 0; r < 16; r++) { st0[r] = 0.f; st1[r] = 0.f; }
            __builtin_amdgcn_s_setprio(1);
            #pragma unroll
            for (int s = 0; s < 4; s++) {
                int co = (2 * s + lh) << 4;
                bf16x8 k0 = *(const bf16x8*)(Kb + r0 * 128 + (co ^ kx));
                bf16x8 k1 = *(const bf16x8*)(Kb + (r0 + 32) * 128 + (co ^ kx));
                st0 = mfma32(k0, qf[s], st0);
                st1 = mfma32(k1, qf[s], st1);
            }
            __builtin_amdgcn_s_setprio(0);

            // --- online softmax (q lane-local), tree reductions ---
            float t8[8];
            #pragma unroll
            for (int j = 0; j < 8; j++)
                t8[j] = fmaxf(fmaxf(st0[2 * j], st0[2 * j + 1]),
                              fmaxf(st1[2 * j], st1[2 * j + 1]));
            float t4a = fmaxf(t8[0], t8[1]), t4b = fmaxf(t8[2], t8[3]);
            float t4c = fmaxf(t8[4], t8[5]), t4d = fmaxf(t8[6], t8[7]);
            float pm = fmaxf(fmaxf(t4a, t4b), fmaxf(t4c, t4d));
            pm = swapmaxf(pm);
            pm *= SM_SCALE;
            if (!__all(pm <= mrun + 8.f)) {      // defer-max (T13)
                float nm = fmaxf(mrun, pm);
                float al = fexp2(mrun - nm);
                lrun *= al; mrun = nm;
                #pragma unroll
                for (int r = 0; r < 16; r++) { ctx0[r] *= al; ctx1[r] *= al; }
            }
            const float mneg = -mrun;
            float rsA = 0.f, rsB = 0.f, rsC = 0.f, rsD = 0.f;
            #pragma unroll
            for (int r = 0; r < 16; r += 2) {
                float e0 = fexp2(fmaf(st0[r],     SM_SCALE, mneg));
                float e1 = fexp2(fmaf(st0[r + 1], SM_SCALE, mneg));
                float e2 = fexp2(fmaf(st1[r],     SM_SCALE, mneg));
                float e3 = fexp2(fmaf(st1[r + 1], SM_SCALE, mneg));
                st0[r] = e0; st0[r + 1] = e1; st1[r] = e2; st1[r + 1] = e3;
                rsA += e0; rsB += e1; rsC += e2; rsD += e3;
            }
            lrun += swapaddf((rsA + rsB) + (rsC + rsD));

            // --- P -> PV B-fragments in-register (T12 exchange) ---
            unsigned X0 = pkbf2(st0[0],  st0[1]),  X1 = pkbf2(st0[2],  st0[3]);
            unsigned X2 = pkbf2(st0[4],  st0[5]),  X3 = pkbf2(st0[6],  st0[7]);
            unsigned X4 = pkbf2(st0[8],  st0[9]),  X5 = pkbf2(st0[10], st0[11]);
            unsigned X6 = pkbf2(st0[12], st0[13]), X7 = pkbf2(st0[14], st0[15]);
            unsigned Y0 = pkbf2(st1[0],  st1[1]),  Y1 = pkbf2(st1[2],  st1[3]);
            unsigned Y2 = pkbf2(st1[4],  st1[5]),  Y3 = pkbf2(st1[6],  st1[7]);
            unsigned Y4 = pkbf2(st1[8],  st1[9]),  Y5 = pkbf2(st1[10], st1[11]);
            unsigned Y6 = pkbf2(st1[12], st1[13]), Y7 = pkbf2(st1[14], st1[15]);
            swap32(X0, X2); swap32(X1, X3);
            swap32(X4, X6); swap32(X5, X7);
            swap32(Y0, Y2); swap32(Y1, Y3);
            swap32(Y4, Y6); swap32(Y5, Y7);
            union W4 { unsigned w[4]; bf16x8 v; };
            W4 pf[4];
            pf[0].w[0]=X0; pf[0].w[1]=X1; pf[0].w[2]=X2; pf[0].w[3]=X3;
            pf[1].w[0]=X4; pf[1].w[1]=X5; pf[1].w[2]=X6; pf[1].w[3]=X7;
            pf[2].w[0]=Y0; pf[2].w[1]=Y1; pf[2].w[2]=Y2; pf[2].w[3]=Y3;
            pf[3].w[0]=Y4; pf[3].w[1]=Y5; pf[3].w[2]=Y6; pf[3].w[3]=Y7;

            // --- PV: ctx^T += V^T x P^T ---
            __builtin_amdgcn_s_setprio(1);
            #pragma unroll
            for (int s = 0; s < 4; s++) {
                int co = (hh * 8 + 2 * s + lh) << 4;
                bf16x8 v0 = *(const bf16x8*)(Vb + r0 * 256 + (co ^ vx));
                bf16x8 v1 = *(const bf16x8*)(Vb + (r0 + 32) * 256 + (co ^ vx));
                ctx0 = mfma32(v0, pf[s].v, ctx0);
                ctx1 = mfma32(v1, pf[s].v, ctx1);
            }
            __builtin_amdgcn_s_setprio(0);
        }

        __syncthreads();
        cur ^= 1;
    }

    // epilogue: out[q][d] = ctx^T * hz / l
    const float hzv = heads_z[hd];
    const float rl = hzv / lrun;
    __bf16* Crow = C + (size_t)(b * SEQ + q) * HID + hd * DH;
    #pragma unroll
    for (int g = 0; g < 4; g++) {
        bf16x4 o0, o1;
        #pragma unroll
        for (int j = 0; j < 4; j++) {
            o0[j] = (__bf16)(ctx0[4 * g + j] * rl);
            o1[j] = (__bf16)(ctx1[4 * g + j] * rl);
        }
        int d0 = 8 * g + 4 * lh;
        *(bf16x4*)(Crow + d0) = o0;
        *(bf16x4*)(Crow + 32 + d0) = o1;
    }
}

extern "C" void kernel_launch(void* const* d_in, const int* in_sizes, int n_in,
                              void* d_out, int out_size, void* d_ws, size_t ws_size,
                              hipStream_t stream)
{
    const float* X    = (const float*)d_in[0];
    const float* Wq   = (const float*)d_in[1];
    const float* bq   = (const float*)d_in[2];
    const float* Wk   = (const float*)d_in[3];
    const float* bk   = (const float*)d_in[4];
    const float* Wv   = (const float*)d_in[5];
    const float* bv   = (const float*)d_in[6];
    const float* Wp   = (const float*)d_in[7];
    const float* bp   = (const float*)d_in[8];
    const float* hz   = (const float*)d_in[9];
    const float* hidz = (const float*)d_in[10];

    __bf16* ws  = (__bf16*)d_ws;
    __bf16* Xb  = ws;
    __bf16* Wqb = Xb  + (size_t)MTOT * HID;
    __bf16* Wkb = Wqb + (size_t)HID * HID;
    __bf16* Wvb = Wkb + (size_t)HID * HID;
    __bf16* Wpb = Wvb + (size_t)HID * HID;
    __bf16* Qb  = Wpb + (size_t)HID * HID;
    __bf16* Kb  = Qb  + (size_t)MTOT * HID;
    __bf16* VTb = Kb  + (size_t)MTOT * HID;
    __bf16* Cb  = VTb + (size_t)MTOT * HID;

    cvt5<<<dim3(2048, 5), 256, 0, stream>>>(X, Wq, Wk, Wv, Wp, Xb, Wqb, Wkb, Wvb, Wpb);

    gemm_qkv<<<dim3(MTOT / 128, HID / 128, 3), 256, 0, stream>>>(
        Xb, Wqb, Wkb, Wvb, bq, bk, bv, Qb, Kb, VTb);

    attn<<<dim3(512), 512, 0, stream>>>(Qb, Kb, VTb, hz, Cb);

    gemm_proj<<<dim3(MTOT / 128, HID / 128), 256, 0, stream>>>(Cb, Wpb, bp, hidz, (float*)d_out);
}

// Round 5
// 197.201 us; speedup vs baseline: 1.7151x; 1.0632x over previous
//
#include <hip/hip_runtime.h>
#include <hip/hip_bf16.h>

#define HID 1024
#define NH 16
#define DH 64
#define SEQ 2048
#define NB 4
#define MTOT (NB*SEQ)   // 8192
#define SM_SCALE 0.18033688f   // 0.125 * log2(e)

typedef __attribute__((ext_vector_type(4))) float f32x4;
typedef __attribute__((ext_vector_type(16))) float f32x16;
typedef __attribute__((ext_vector_type(8))) __bf16 bf16x8;
typedef __attribute__((ext_vector_type(4))) __bf16 bf16x4;
typedef __attribute__((ext_vector_type(2))) __bf16 bf16x2;
typedef __attribute__((ext_vector_type(2))) int i32x2;

__device__ __forceinline__ f32x4 mfma16(bf16x8 a, bf16x8 b, f32x4 c) {
    return __builtin_amdgcn_mfma_f32_16x16x32_bf16(a, b, c, 0, 0, 0);
}
__device__ __forceinline__ f32x16 mfma32(bf16x8 a, bf16x8 b, f32x16 c) {
    return __builtin_amdgcn_mfma_f32_32x32x16_bf16(a, b, c, 0, 0, 0);
}

__device__ __forceinline__ void gload16(const void* g, void* l) {
    __builtin_amdgcn_global_load_lds(
        (const __attribute__((address_space(1))) unsigned int*)g,
        (__attribute__((address_space(3))) unsigned int*)l, 16, 0, 0);
}

__device__ __forceinline__ float fexp2(float x) {
#if __has_builtin(__builtin_amdgcn_exp2f)
    return __builtin_amdgcn_exp2f(x);
#else
    return exp2f(x);
#endif
}

__device__ __forceinline__ unsigned pkbf2(float lo, float hi) {
    union { bf16x2 v; unsigned u; } c;
    c.v = (bf16x2){ (__bf16)lo, (__bf16)hi };
    return c.u;
}

#define F3(a,b,c) fmaxf(fmaxf((a),(b)),(c))   // -> v_max3_f32

// v_permlane32_swap semantics across the lane32 boundary.
__device__ __forceinline__ void swap32(unsigned &a, unsigned &b) {
#if __has_builtin(__builtin_amdgcn_permlane32_swap)
    i32x2 r = __builtin_amdgcn_permlane32_swap((int)a, (int)b, false, false);
    a = (unsigned)r.x; b = (unsigned)r.y;
#else
    const bool hi = (threadIdx.x & 32) != 0;
    unsigned ta = __shfl_xor(a, 32), tb = __shfl_xor(b, 32);
    unsigned na = hi ? tb : a;
    unsigned nb = hi ? b : ta;
    a = na; b = nb;
#endif
}

__device__ __forceinline__ float swapmaxf(float x) {
    unsigned a = __float_as_uint(x), b = a;
    swap32(a, b);
    return fmaxf(__uint_as_float(a), __uint_as_float(b));
}

// ---------------- fused fp32 -> bf16 convert ----------------
__global__ __launch_bounds__(256)
void cvt5(const float* __restrict__ X,  const float* __restrict__ Wq,
          const float* __restrict__ Wk, const float* __restrict__ Wv,
          const float* __restrict__ Wp,
          __bf16* __restrict__ Xb,  __bf16* __restrict__ Wqb,
          __bf16* __restrict__ Wkb, __bf16* __restrict__ Wvb,
          __bf16* __restrict__ Wpb)
{
    const float* src; __bf16* dst; int n;
    switch (blockIdx.y) {
        case 0:  src = X;  dst = Xb;  n = MTOT * HID; break;
        case 1:  src = Wq; dst = Wqb; n = HID * HID;  break;
        case 2:  src = Wk; dst = Wkb; n = HID * HID;  break;
        case 3:  src = Wv; dst = Wvb; n = HID * HID;  break;
        default: src = Wp; dst = Wpb; n = HID * HID;  break;
    }
    const int stride = gridDim.x * 256 * 4;
    for (int i = (blockIdx.x * 256 + threadIdx.x) * 4; i < n; i += stride) {
        float4 v = *(const float4*)(src + i);
        bf16x4 o = { (__bf16)v.x, (__bf16)v.y, (__bf16)v.z, (__bf16)v.w };
        *(bf16x4*)(dst + i) = o;
    }
}

// ---------------- QKV GEMM (grid.z = mode 0:Q 1:K 2:V) ----------------
// Q is pre-scaled by SM_SCALE; V written transposed with packed bf16x4 stores.
__global__ __launch_bounds__(256)
void gemm_qkv(const __bf16* __restrict__ A,
              const __bf16* __restrict__ Wq, const __bf16* __restrict__ Wk,
              const __bf16* __restrict__ Wv,
              const float* __restrict__ bq, const float* __restrict__ bk,
              const float* __restrict__ bv,
              __bf16* __restrict__ Qo, __bf16* __restrict__ Ko, __bf16* __restrict__ Vo)
{
    __shared__ __bf16 As[128 * 32];
    __shared__ __bf16 Bs[128 * 32];
    const int mode = blockIdx.z;
    const __bf16* W    = mode == 0 ? Wq : mode == 1 ? Wk : Wv;
    const float*  bias = mode == 0 ? bq : mode == 1 ? bk : bv;

    const int tid  = threadIdx.x;
    const int lane = tid & 63, wid = tid >> 6;
    const int m0 = blockIdx.x * 128;
    const int n0 = blockIdx.y * 128;
    const int wm = (wid >> 1) * 64, wn = (wid & 1) * 64;

    f32x4 acc[4][4];
    #pragma unroll
    for (int i = 0; i < 4; i++)
        #pragma unroll
        for (int j = 0; j < 4; j++) acc[i][j] = (f32x4){0.f, 0.f, 0.f, 0.f};

    for (int kt = 0; kt < HID; kt += 32) {
        #pragma unroll
        for (int i = 0; i < 2; i++) {
            int c = wid * 128 + i * 64 + lane;
            int row = c >> 2, slot = c & 3;
            int ss = slot ^ (row & 3);
            gload16(A + (size_t)(m0 + row) * HID + kt + ss * 8, (char*)As + c * 16);
            gload16(W + (size_t)(n0 + row) * HID + kt + ss * 8, (char*)Bs + c * 16);
        }
        __syncthreads();

        bf16x8 af[4], bfr[4];
        #pragma unroll
        for (int mi = 0; mi < 4; mi++) {
            int row = wm + mi * 16 + (lane & 15);
            int off = row * 64 + (((lane >> 4) * 16) ^ ((row & 3) << 4));
            af[mi] = *(const bf16x8*)((const char*)As + off);
        }
        #pragma unroll
        for (int ni = 0; ni < 4; ni++) {
            int row = wn + ni * 16 + (lane & 15);
            int off = row * 64 + (((lane >> 4) * 16) ^ ((row & 3) << 4));
            bfr[ni] = *(const bf16x8*)((const char*)Bs + off);
        }
        #pragma unroll
        for (int mi = 0; mi < 4; mi++)
            #pragma unroll
            for (int ni = 0; ni < 4; ni++)
                acc[mi][ni] = mfma16(af[mi], bfr[ni], acc[mi][ni]);
        __syncthreads();
    }

    if (mode == 2) {
        // V^T: 4 r-regs = 4 consecutive s -> packed 8B stores
        #pragma unroll
        for (int mi = 0; mi < 4; mi++)
            #pragma unroll
            for (int ni = 0; ni < 4; ni++) {
                int m = m0 + wm + mi * 16 + ((lane >> 4) * 4);
                int n = n0 + wn + ni * 16 + (lane & 15);
                int b = m >> 11, s = m & (SEQ - 1);
                int h = n >> 6,  d = n & 63;
                bf16x4 o;
                #pragma unroll
                for (int r = 0; r < 4; r++) o[r] = (__bf16)(acc[mi][ni][r] + bias[n]);
                *(bf16x4*)(Vo + ((size_t)(b * NH + h) * DH + d) * SEQ + s) = o;
            }
    } else {
        const float qs = (mode == 0) ? SM_SCALE : 1.0f;
        __bf16* Og = (mode == 0) ? Qo : Ko;
        #pragma unroll
        for (int mi = 0; mi < 4; mi++)
            #pragma unroll
            for (int ni = 0; ni < 4; ni++)
                #pragma unroll
                for (int r = 0; r < 4; r++) {
                    int m = m0 + wm + mi * 16 + ((lane >> 4) * 4) + r;
                    int n = n0 + wn + ni * 16 + (lane & 15);
                    float v = (acc[mi][ni][r] + bias[n]) * qs;
                    int b = m >> 11, s = m & (SEQ - 1);
                    int h = n >> 6,  d = n & 63;
                    Og[((size_t)(b * NH + h) * SEQ + s) * DH + d] = (__bf16)v;
                }
    }
}

// ---------------- proj GEMM: out fp32 = (A W^T + bias) * hidden_z ----------------
__global__ __launch_bounds__(256)
void gemm_proj(const __bf16* __restrict__ A, const __bf16* __restrict__ W,
               const float* __restrict__ bias, const float* __restrict__ hz,
               float* __restrict__ outp)
{
    __shared__ __bf16 As[128 * 32];
    __shared__ __bf16 Bs[128 * 32];
    const int tid  = threadIdx.x;
    const int lane = tid & 63, wid = tid >> 6;
    const int m0 = blockIdx.x * 128;
    const int n0 = blockIdx.y * 128;
    const int wm = (wid >> 1) * 64, wn = (wid & 1) * 64;

    f32x4 acc[4][4];
    #pragma unroll
    for (int i = 0; i < 4; i++)
        #pragma unroll
        for (int j = 0; j < 4; j++) acc[i][j] = (f32x4){0.f, 0.f, 0.f, 0.f};

    for (int kt = 0; kt < HID; kt += 32) {
        #pragma unroll
        for (int i = 0; i < 2; i++) {
            int c = wid * 128 + i * 64 + lane;
            int row = c >> 2, slot = c & 3;
            int ss = slot ^ (row & 3);
            gload16(A + (size_t)(m0 + row) * HID + kt + ss * 8, (char*)As + c * 16);
            gload16(W + (size_t)(n0 + row) * HID + kt + ss * 8, (char*)Bs + c * 16);
        }
        __syncthreads();

        bf16x8 af[4], bfr[4];
        #pragma unroll
        for (int mi = 0; mi < 4; mi++) {
            int row = wm + mi * 16 + (lane & 15);
            int off = row * 64 + (((lane >> 4) * 16) ^ ((row & 3) << 4));
            af[mi] = *(const bf16x8*)((const char*)As + off);
        }
        #pragma unroll
        for (int ni = 0; ni < 4; ni++) {
            int row = wn + ni * 16 + (lane & 15);
            int off = row * 64 + (((lane >> 4) * 16) ^ ((row & 3) << 4));
            bfr[ni] = *(const bf16x8*)((const char*)Bs + off);
        }
        #pragma unroll
        for (int mi = 0; mi < 4; mi++)
            #pragma unroll
            for (int ni = 0; ni < 4; ni++)
                acc[mi][ni] = mfma16(af[mi], bfr[ni], acc[mi][ni]);
        __syncthreads();
    }

    #pragma unroll
    for (int mi = 0; mi < 4; mi++)
        #pragma unroll
        for (int ni = 0; ni < 4; ni++)
            #pragma unroll
            for (int r = 0; r < 4; r++) {
                int m = m0 + wm + mi * 16 + ((lane >> 4) * 4) + r;
                int n = n0 + wn + ni * 16 + (lane & 15);
                outp[(size_t)m * HID + n] = (acc[mi][ni][r] + bias[n]) * hz[n];
            }
}

// ---------------- flash attention: 32x32 MFMA, KVB=128, XCD-local K/V ----------------
#define KVB 128

__global__ __launch_bounds__(512, 4)
void attn(const __bf16* __restrict__ Q, const __bf16* __restrict__ K,
          const __bf16* __restrict__ VT, const float* __restrict__ heads_z,
          __bf16* __restrict__ C)
{
    __shared__ __bf16 Ks[2][KVB * 64];   // [kv][64 d]   rows 128 B
    __shared__ __bf16 Vs[2][64 * KVB];   // [d][128 kv]  rows 256 B
    const int tid = threadIdx.x, lane = tid & 63, wid = tid >> 6;
    const int lh = lane >> 5;
    const int id = blockIdx.x;
    const int bh = (id & 7) | ((id >> 6) << 3);   // bijective: bh&7 = id&7 -> same XCD
    const int qb = (id >> 3) & 7;
    const int b = bh >> 4, hd = bh & 15;
    const __bf16* Qg = Q + (size_t)bh * SEQ * DH;
    const __bf16* Kg = K + (size_t)bh * SEQ * DH;
    const __bf16* Vg = VT + (size_t)bh * DH * SEQ;
    const int q = qb * 256 + wid * 32 + (lane & 31);
    const int r0 = lane & 31;
    const int kx = (r0 & 7) << 4;    // K row-XOR (128B rows)
    const int vx = (r0 & 15) << 4;   // V row-XOR (256B rows)

    // ones A-fragment for MFMA row-sums
    bf16x8 ones8;
    #pragma unroll
    for (int j = 0; j < 8; j++) ones8[j] = (__bf16)1.0f;

    // Q B-fragments (Q pre-scaled by SM_SCALE in the GEMM)
    bf16x8 qf[4];
    #pragma unroll
    for (int s = 0; s < 4; s++)
        qf[s] = *(const bf16x8*)(Qg + (size_t)q * DH + s * 16 + lh * 8);

    f32x16 ctx0, ctx1;   // ctx^T: col=q, rows d=0..31 (ctx0), 32..63 (ctx1)
    #pragma unroll
    for (int r = 0; r < 16; r++) { ctx0[r] = 0.f; ctx1[r] = 0.f; }
    float mrun = -1e30f, lrun = 0.f;

    const int kr0 = tid >> 3,          kss0 = (tid & 7) ^ (kr0 & 7);
    const int kr1 = (tid + 512) >> 3,  kss1 = (tid & 7) ^ (kr1 & 7);
    const int vr0 = tid >> 4,          vss0 = (tid & 15) ^ (vr0 & 15);
    const int vr1 = (tid + 512) >> 4,  vss1 = (tid & 15) ^ (vr1 & 15);

    gload16(Kg + (size_t)kr0 * DH + kss0 * 8, (char*)&Ks[0][0] + tid * 16);
    gload16(Kg + (size_t)kr1 * DH + kss1 * 8, (char*)&Ks[0][0] + (tid + 512) * 16);
    gload16(Vg + (size_t)vr0 * SEQ + 0 + vss0 * 8, (char*)&Vs[0][0] + tid * 16);
    gload16(Vg + (size_t)vr1 * SEQ + 0 + vss1 * 8, (char*)&Vs[0][0] + (tid + 512) * 16);
    __syncthreads();

    int cur = 0;
    for (int kv0 = 0; kv0 < SEQ; kv0 += KVB) {
        if (kv0 + KVB < SEQ) {
            int nx = kv0 + KVB;
            gload16(Kg + (size_t)(nx + kr0) * DH + kss0 * 8, (char*)&Ks[cur ^ 1][0] + tid * 16);
            gload16(Kg + (size_t)(nx + kr1) * DH + kss1 * 8, (char*)&Ks[cur ^ 1][0] + (tid + 512) * 16);
            gload16(Vg + (size_t)vr0 * SEQ + nx + vss0 * 8, (char*)&Vs[cur ^ 1][0] + tid * 16);
            gload16(Vg + (size_t)vr1 * SEQ + nx + vss1 * 8, (char*)&Vs[cur ^ 1][0] + (tid + 512) * 16);
        }

        #pragma unroll
        for (int hh = 0; hh < 2; hh++) {          // two 64-wide kv halves
            const char* Kb = (const char*)&Ks[cur][0] + hh * 64 * 128;
            const char* Vb = (const char*)&Vs[cur][0];

            // --- QK^T: st[kv][q] ---
            f32x16 st0, st1;
            #pragma unroll
            for (int r = 0; r < 16; r++) { st0[r] = 0.f; st1[r] = 0.f; }
            __builtin_amdgcn_s_setprio(1);
            #pragma unroll
            for (int s = 0; s < 4; s++) {
                int co = (2 * s + lh) << 4;
                bf16x8 k0 = *(const bf16x8*)(Kb + r0 * 128 + (co ^ kx));
                bf16x8 k1 = *(const bf16x8*)(Kb + (r0 + 32) * 128 + (co ^ kx));
                st0 = mfma32(k0, qf[s], st0);
                st1 = mfma32(k1, qf[s], st1);
            }
            __builtin_amdgcn_s_setprio(0);

            // --- online softmax: lane-local max3 tree; swapmax only on trigger ---
            float l1[11];
            l1[0] = F3(st0[0],  st0[1],  st0[2]);
            l1[1] = F3(st0[3],  st0[4],  st0[5]);
            l1[2] = F3(st0[6],  st0[7],  st0[8]);
            l1[3] = F3(st0[9],  st0[10], st0[11]);
            l1[4] = F3(st0[12], st0[13], st0[14]);
            l1[5] = F3(st0[15], st1[0],  st1[1]);
            l1[6] = F3(st1[2],  st1[3],  st1[4]);
            l1[7] = F3(st1[5],  st1[6],  st1[7]);
            l1[8] = F3(st1[8],  st1[9],  st1[10]);
            l1[9] = F3(st1[11], st1[12], st1[13]);
            l1[10] = fmaxf(st1[14], st1[15]);
            float l2a = F3(l1[0], l1[1], l1[2]);
            float l2b = F3(l1[3], l1[4], l1[5]);
            float l2c = F3(l1[6], l1[7], l1[8]);
            float l2d = fmaxf(l1[9], l1[10]);
            float pml = F3(F3(l2a, l2b, l2c), l2d, mrun) - 0.f;  // include mrun
            if (!__all(pml <= mrun + 8.f)) {      // defer-max (T13)
                float pm = swapmaxf(pml);
                float nm = fmaxf(mrun, pm);
                float al = fexp2(mrun - nm);
                lrun *= al; mrun = nm;
                #pragma unroll
                for (int r = 0; r < 16; r++) { ctx0[r] *= al; ctx1[r] *= al; }
            }
            const float mneg = -mrun;
            #pragma unroll
            for (int r = 0; r < 16; r++) {
                st0[r] = fexp2(st0[r] + mneg);
                st1[r] = fexp2(st1[r] + mneg);
            }

            // --- P -> PV B-fragments in-register (T12 exchange) ---
            unsigned X0 = pkbf2(st0[0],  st0[1]),  X1 = pkbf2(st0[2],  st0[3]);
            unsigned X2 = pkbf2(st0[4],  st0[5]),  X3 = pkbf2(st0[6],  st0[7]);
            unsigned X4 = pkbf2(st0[8],  st0[9]),  X5 = pkbf2(st0[10], st0[11]);
            unsigned X6 = pkbf2(st0[12], st0[13]), X7 = pkbf2(st0[14], st0[15]);
            unsigned Y0 = pkbf2(st1[0],  st1[1]),  Y1 = pkbf2(st1[2],  st1[3]);
            unsigned Y2 = pkbf2(st1[4],  st1[5]),  Y3 = pkbf2(st1[6],  st1[7]);
            unsigned Y4 = pkbf2(st1[8],  st1[9]),  Y5 = pkbf2(st1[10], st1[11]);
            unsigned Y6 = pkbf2(st1[12], st1[13]), Y7 = pkbf2(st1[14], st1[15]);
            swap32(X0, X2); swap32(X1, X3);
            swap32(X4, X6); swap32(X5, X7);
            swap32(Y0, Y2); swap32(Y1, Y3);
            swap32(Y4, Y6); swap32(Y5, Y7);
            union W4 { unsigned w[4]; bf16x8 v; };
            W4 pf[4];
            pf[0].w[0]=X0; pf[0].w[1]=X1; pf[0].w[2]=X2; pf[0].w[3]=X3;
            pf[1].w[0]=X4; pf[1].w[1]=X5; pf[1].w[2]=X6; pf[1].w[3]=X7;
            pf[2].w[0]=Y0; pf[2].w[1]=Y1; pf[2].w[2]=Y2; pf[2].w[3]=Y3;
            pf[3].w[0]=Y4; pf[3].w[1]=Y5; pf[3].w[2]=Y6; pf[3].w[3]=Y7;

            // --- row-sum on the MFMA pipe: st0 is dead, reuse it ---
            st0[0] = 0.f;
            #pragma unroll
            for (int s = 0; s < 4; s++) st0 = mfma32(ones8, pf[s].v, st0);

            // --- PV: ctx^T += V^T x P^T ---
            __builtin_amdgcn_s_setprio(1);
            #pragma unroll
            for (int s = 0; s < 4; s++) {
                int co = (hh * 8 + 2 * s + lh) << 4;
                bf16x8 v0 = *(const bf16x8*)(Vb + r0 * 256 + (co ^ vx));
                bf16x8 v1 = *(const bf16x8*)(Vb + (r0 + 32) * 256 + (co ^ vx));
                ctx0 = mfma32(v0, pf[s].v, ctx0);
                ctx1 = mfma32(v1, pf[s].v, ctx1);
            }
            __builtin_amdgcn_s_setprio(0);

            lrun += st0[0];
        }

        __syncthreads();
        cur ^= 1;
    }

    // epilogue
    const float hzv = heads_z[hd];
    const float rl = hzv / lrun;
    __bf16* Crow = C + (size_t)(b * SEQ + q) * HID + hd * DH;
    #pragma unroll
    for (int g = 0; g < 4; g++) {
        bf16x4 o0, o1;
        #pragma unroll
        for (int j = 0; j < 4; j++) {
            o0[j] = (__bf16)(ctx0[4 * g + j] * rl);
            o1[j] = (__bf16)(ctx1[4 * g + j] * rl);
        }
        int d0 = 8 * g + 4 * lh;
        *(bf16x4*)(Crow + d0) = o0;
        *(bf16x4*)(Crow + 32 + d0) = o1;
    }
}

extern "C" void kernel_launch(void* const* d_in, const int* in_sizes, int n_in,
                              void* d_out, int out_size, void* d_ws, size_t ws_size,
                              hipStream_t stream)
{
    const float* X    = (const float*)d_in[0];
    const float* Wq   = (const float*)d_in[1];
    const float* bq   = (const float*)d_in[2];
    const float* Wk   = (const float*)d_in[3];
    const float* bk   = (const float*)d_in[4];
    const float* Wv   = (const float*)d_in[5];
    const float* bv   = (const float*)d_in[6];
    const float* Wp   = (const float*)d_in[7];
    const float* bp   = (const float*)d_in[8];
    const float* hz   = (const float*)d_in[9];
    const float* hidz = (const float*)d_in[10];

    __bf16* ws  = (__bf16*)d_ws;
    __bf16* Xb  = ws;
    __bf16* Wqb = Xb  + (size_t)MTOT * HID;
    __bf16* Wkb = Wqb + (size_t)HID * HID;
    __bf16* Wvb = Wkb + (size_t)HID * HID;
    __bf16* Wpb = Wvb + (size_t)HID * HID;
    __bf16* Qb  = Wpb + (size_t)HID * HID;
    __bf16* Kb  = Qb  + (size_t)MTOT * HID;
    __bf16* VTb = Kb  + (size_t)MTOT * HID;
    __bf16* Cb  = VTb + (size_t)MTOT * HID;

    cvt5<<<dim3(2048, 5), 256, 0, stream>>>(X, Wq, Wk, Wv, Wp, Xb, Wqb, Wkb, Wvb, Wpb);

    gemm_qkv<<<dim3(MTOT / 128, HID / 128, 3), 256, 0, stream>>>(
        Xb, Wqb, Wkb, Wvb, bq, bk, bv, Qb, Kb, VTb);

    attn<<<dim3(512), 512, 0, stream>>>(Qb, Kb, VTb, hz, Cb);

    gemm_proj<<<dim3(MTOT / 128, HID / 128), 256, 0, stream>>>(Cb, Wpb, bp, hidz, (float*)d_out);
}